// Round 1
// baseline (318.664 us; speedup 1.0000x reference)
//
#include <hip/hip_runtime.h>
#include <hip/hip_bf16.h>

#define NE 100000
#define NK 16
#define ND 128

typedef __bf16 bf16_t;
typedef bf16_t bf16x8 __attribute__((ext_vector_type(8)));
typedef float f32x4 __attribute__((ext_vector_type(4)));

__device__ __forceinline__ unsigned short f2bf(float f) {
  bf16_t h = (bf16_t)f;
  return __builtin_bit_cast(unsigned short, h);
}
__device__ __forceinline__ float bf2f(unsigned int bits) {
  return __builtin_bit_cast(float, bits << 16);
}

// ---------------------------------------------------------------------------
// K0: fold the update-MLP second path:
//   Wp[o][o'] = sum_p Um[o][p] * mW2[p][o']   (Um = uW1[:,128:256])
//   bp[o]     = ub1[o] + sum_p Um[o][p] * mb2[p]
// ---------------------------------------------------------------------------
__global__ void k_fold(const float* __restrict__ uW1, const float* __restrict__ mW2,
                       const float* __restrict__ ub1, const float* __restrict__ mb2,
                       unsigned short* __restrict__ Wp, float* __restrict__ bp)
{
  const int o = blockIdx.x, t = threadIdx.x;
  float acc = 0.f;
  for (int p = 0; p < 128; ++p)
    acc += uW1[o * 256 + 128 + p] * mW2[p * 128 + t];
  Wp[o * 128 + t] = f2bf(acc);
  if (t == 0) {
    float b = ub1[o];
    for (int p = 0; p < 128; ++p) b += uW1[o * 256 + 128 + p] * mb2[p];
    bp[o] = b;
  }
}

// ---------------------------------------------------------------------------
// K1: one GEMM pass over X producing three 128-wide outputs per edge:
//   S  = X @ Wi^T + mb1   (bf16)   Wi = mW1[:, :128]
//   Z  = X @ Wj^T         (bf16)   Wj = mW1[:, 128:]
//   T1 = X @ Ui^T + bp    (f32, written into d_out as scratch)
// Wave handles 16 edges; 24 n-tiles of 16 cols; K=128 in 4 MFMA steps.
// ---------------------------------------------------------------------------
__global__ __launch_bounds__(256) void k_gemm1(
    const float* __restrict__ X, const float* __restrict__ mW1,
    const float* __restrict__ uW1, const float* __restrict__ mb1,
    const float* __restrict__ bp,
    unsigned short* __restrict__ Sb, unsigned short* __restrict__ Zb,
    float* __restrict__ T1)
{
  const int tid = threadIdx.x, wid = tid >> 6, lane = tid & 63;
  const int r = lane & 15, q = lane >> 4;
  const long e0 = ((long)blockIdx.x * 4 + wid) * 16;
  if (e0 >= NE) return;

  // A-frags: lane reads X[e0 + r][kk*32 + q*8 + i], convert f32->bf16
  bf16x8 a[4];
  {
    const float* xp = X + (e0 + r) * ND + q * 8;
#pragma unroll
    for (int kk = 0; kk < 4; ++kk) {
      bf16x8 t;
#pragma unroll
      for (int i = 0; i < 8; ++i) t[i] = (bf16_t)xp[kk * 32 + i];
      a[kk] = t;
    }
  }

  f32x4 acc[24];
#pragma unroll
  for (int nt = 0; nt < 24; ++nt) acc[nt] = f32x4{0.f, 0.f, 0.f, 0.f};

#pragma unroll
  for (int nt = 0; nt < 24; ++nt) {
    const float* wrow;
    if (nt < 8)       wrow = mW1 + (nt * 16 + r) * 256 + q * 8;          // Wi
    else if (nt < 16) wrow = mW1 + ((nt - 8) * 16 + r) * 256 + 128 + q * 8; // Wj
    else              wrow = uW1 + ((nt - 16) * 16 + r) * 256 + q * 8;   // Ui
#pragma unroll
    for (int kk = 0; kk < 4; ++kk) {
      bf16x8 b;
#pragma unroll
      for (int i = 0; i < 8; ++i) b[i] = (bf16_t)wrow[kk * 32 + i];
      acc[nt] = __builtin_amdgcn_mfma_f32_16x16x32_bf16(a[kk], b, acc[nt], 0, 0, 0);
    }
  }

  // Epilogue: D layout col = lane&15, row = (lane>>4)*4 + i
#pragma unroll
  for (int nt = 0; nt < 24; ++nt) {
    const int col = (nt & 7) * 16 + r;
#pragma unroll
    for (int i = 0; i < 4; ++i) {
      const long e = e0 + q * 4 + i;
      const float v = acc[nt][i];
      if (nt < 8)       Sb[e * ND + col] = f2bf(v + mb1[col]);
      else if (nt < 16) Zb[e * ND + col] = f2bf(v);
      else              T1[e * ND + col] = v + bp[col];
    }
  }
}

// ---------------------------------------------------------------------------
// K2: hbar[e] = (1/16) * sum_k relu(S[e] + Z[adj[e][k]])
// One wave per edge; lane covers dims {2*lane, 2*lane+1}; row gathers are
// 256B contiguous (64 lanes x 1 dword of 2 bf16). Z table is L3-resident.
// ---------------------------------------------------------------------------
__global__ __launch_bounds__(256) void k_gather(
    const unsigned short* __restrict__ Zb, const unsigned short* __restrict__ Sb,
    const int* __restrict__ adj, unsigned short* __restrict__ Hb)
{
  const int tid = threadIdx.x, wid = tid >> 6, lane = tid & 63;
  const long e = (long)blockIdx.x * 4 + wid;
  if (e >= NE) return;
  const int d0 = lane * 2;

  const unsigned sbits = *(const unsigned*)(Sb + e * ND + d0);
  const float s0 = bf2f(sbits & 0xffffu);
  const float s1 = bf2f(sbits >> 16);

  float acc0 = 0.f, acc1 = 0.f;
  const int* ar = adj + e * NK;
#pragma unroll
  for (int k = 0; k < NK; ++k) {
    const int n = ar[k];
    const unsigned z = *(const unsigned*)(Zb + (long)n * ND + d0);
    acc0 += fmaxf(s0 + bf2f(z & 0xffffu), 0.f);
    acc1 += fmaxf(s1 + bf2f(z >> 16), 0.f);
  }
  const unsigned outw =
      (unsigned)f2bf(acc0 * 0.0625f) | ((unsigned)f2bf(acc1 * 0.0625f) << 16);
  *(unsigned*)(Hb + e * ND + d0) = outw;
}

// ---------------------------------------------------------------------------
// K3: u = relu(T1 + hbar @ Wp^T); out = u @ uW2^T + ub2
// Two chained MFMAs per wave-tile of 16 edges; u routed through per-wave
// XOR-swizzled LDS to convert D-layout -> A-layout. T1 aliases d_out (each
// wave reads-then-writes only its own 16 edges).
// ---------------------------------------------------------------------------
__global__ __launch_bounds__(256) void k_gemm2(
    const unsigned short* __restrict__ Hb, const unsigned short* __restrict__ Wp,
    const float* __restrict__ uW2, const float* __restrict__ ub2,
    float* __restrict__ IO)
{
  __shared__ unsigned short ut[4][16 * ND];
  const int tid = threadIdx.x, wid = tid >> 6, lane = tid & 63;
  const int r = lane & 15, q = lane >> 4;
  const long e0 = ((long)blockIdx.x * 4 + wid) * 16;
  if (e0 >= NE) return;

  // A-frags from hbar (already bf16 in memory)
  bf16x8 a[4];
#pragma unroll
  for (int kk = 0; kk < 4; ++kk)
    a[kk] = *(const bf16x8*)(Hb + (e0 + r) * ND + kk * 32 + q * 8);

  f32x4 acc[8];
#pragma unroll
  for (int nt = 0; nt < 8; ++nt) acc[nt] = f32x4{0.f, 0.f, 0.f, 0.f};
#pragma unroll
  for (int nt = 0; nt < 8; ++nt) {
#pragma unroll
    for (int kk = 0; kk < 4; ++kk) {
      const bf16x8 b = *(const bf16x8*)(Wp + (nt * 16 + r) * ND + kk * 32 + q * 8);
      acc[nt] = __builtin_amdgcn_mfma_f32_16x16x32_bf16(a[kk], b, acc[nt], 0, 0, 0);
    }
  }

  // u = relu(T1 + acc), write bf16 into swizzled LDS tile [16 rows][128 cols]
  unsigned short* lds = ut[wid];
#pragma unroll
  for (int nt = 0; nt < 8; ++nt) {
    const int col = nt * 16 + r;
#pragma unroll
    for (int i = 0; i < 4; ++i) {
      const int erow = q * 4 + i;
      const float t = IO[(e0 + erow) * ND + col];
      const unsigned short ub = f2bf(fmaxf(t + acc[nt][i], 0.f));
      const int byteoff = erow * 256 + ((col * 2) ^ ((erow & 7) << 4));
      lds[byteoff >> 1] = ub;
    }
  }

  // Second GEMM: A-frags for u from LDS (same XOR swizzle, 16B aligned)
  bf16x8 a2[4];
#pragma unroll
  for (int kk = 0; kk < 4; ++kk) {
    const int byteoff = r * 256 + ((kk * 64 + q * 16) ^ ((r & 7) << 4));
    a2[kk] = *(const bf16x8*)((const char*)lds + byteoff);
  }

  f32x4 o[8];
#pragma unroll
  for (int nt = 0; nt < 8; ++nt) o[nt] = f32x4{0.f, 0.f, 0.f, 0.f};
#pragma unroll
  for (int nt = 0; nt < 8; ++nt) {
    const float* wrow = uW2 + (nt * 16 + r) * ND + q * 8;
#pragma unroll
    for (int kk = 0; kk < 4; ++kk) {
      bf16x8 b;
#pragma unroll
      for (int i = 0; i < 8; ++i) b[i] = (bf16_t)wrow[kk * 32 + i];
      o[nt] = __builtin_amdgcn_mfma_f32_16x16x32_bf16(a2[kk], b, o[nt], 0, 0, 0);
    }
  }

#pragma unroll
  for (int nt = 0; nt < 8; ++nt) {
    const int col = nt * 16 + r;
    const float bias = ub2[col];
#pragma unroll
    for (int i = 0; i < 4; ++i)
      IO[(e0 + q * 4 + i) * ND + col] = o[nt][i] + bias;
  }
}

extern "C" void kernel_launch(void* const* d_in, const int* in_sizes, int n_in,
                              void* d_out, int out_size, void* d_ws, size_t ws_size,
                              hipStream_t stream)
{
  (void)in_sizes; (void)n_in; (void)out_size; (void)ws_size;
  const float* X   = (const float*)d_in[0];
  const int*   adj = (const int*)d_in[1];
  const float* mW1 = (const float*)d_in[2];
  const float* mb1 = (const float*)d_in[3];
  const float* mW2 = (const float*)d_in[4];
  const float* mb2 = (const float*)d_in[5];
  const float* uW1 = (const float*)d_in[6];
  const float* ub1 = (const float*)d_in[7];
  const float* uW2 = (const float*)d_in[8];
  const float* ub2 = (const float*)d_in[9];
  float* out = (float*)d_out;

  unsigned short* ws16 = (unsigned short*)d_ws;
  unsigned short* Sb = ws16;                            // E*D bf16
  unsigned short* Zb = ws16 + (size_t)NE * ND;          // E*D bf16
  unsigned short* Hb = ws16 + 2 * (size_t)NE * ND;      // E*D bf16
  unsigned short* Wp = ws16 + 3 * (size_t)NE * ND;      // 128*128 bf16
  float* bp = (float*)(Wp + 128 * 128);                 // 128 f32

  k_fold<<<128, 128, 0, stream>>>(uW1, mW2, ub1, mb2, Wp, bp);

  const int nblk_gemm = (NE / 16 + 3) / 4;  // 1563
  k_gemm1<<<nblk_gemm, 256, 0, stream>>>(X, mW1, uW1, mb1, bp, Sb, Zb, out);

  const int nblk_gather = (NE + 3) / 4;     // 25000
  k_gather<<<nblk_gather, 256, 0, stream>>>(Zb, Sb, adj, Hb);

  k_gemm2<<<nblk_gemm, 256, 0, stream>>>(Hb, Wp, uW2, ub2, out);
}

// Round 2
// 225.003 us; speedup vs baseline: 1.4163x; 1.4163x over previous
//
#include <hip/hip_runtime.h>
#include <hip/hip_bf16.h>

#define NE 100000
#define NK 16
#define ND 128

typedef __bf16 bf16_t;
typedef bf16_t bf16x8 __attribute__((ext_vector_type(8)));
typedef bf16_t bf16x4 __attribute__((ext_vector_type(4)));
typedef float f32x4 __attribute__((ext_vector_type(4)));
typedef unsigned short u16;

__device__ __forceinline__ u16 f2bf(float f) {
  bf16_t h = (bf16_t)f;
  return __builtin_bit_cast(u16, h);
}
__device__ __forceinline__ float bf2f(unsigned int bits) {
  return __builtin_bit_cast(float, bits << 16);
}

// ---------------------------------------------------------------------------
// k_prep: bf16-convert all weight matrices (row-major [128][128]) and fold
//   Wp = Um @ mW2          (Um = uW1[:,128:256])
//   bp = ub1 + Um @ mb2
// ---------------------------------------------------------------------------
__global__ void k_prep(const float* __restrict__ mW1, const float* __restrict__ uW1,
                       const float* __restrict__ uW2, const float* __restrict__ mW2,
                       const float* __restrict__ ub1, const float* __restrict__ mb2,
                       u16* __restrict__ Wi_b, u16* __restrict__ Wj_b,
                       u16* __restrict__ Ui_b, u16* __restrict__ Wp_b,
                       u16* __restrict__ W2_b, float* __restrict__ bp)
{
  const int o = blockIdx.x, t = threadIdx.x;
  Wi_b[o * ND + t] = f2bf(mW1[o * 256 + t]);
  Wj_b[o * ND + t] = f2bf(mW1[o * 256 + 128 + t]);
  Ui_b[o * ND + t] = f2bf(uW1[o * 256 + t]);
  W2_b[o * ND + t] = f2bf(uW2[o * ND + t]);
  float acc = 0.f;
  for (int p = 0; p < 128; ++p)
    acc += uW1[o * 256 + 128 + p] * mW2[p * 128 + t];
  Wp_b[o * ND + t] = f2bf(acc);
  if (t == 0) {
    float b = ub1[o];
    for (int p = 0; p < 128; ++p) b += uW1[o * 256 + 128 + p] * mb2[p];
    bp[o] = b;
  }
}

// ---------------------------------------------------------------------------
// k1: per 16-edge wave-tile:
//   Xb = bf16(X)            (written at stride 256 into d_out's rows)
//   S  = X @ Wi^T + mb1     (bf16)
//   Z  = X @ Wj^T           (bf16)
// mfma(A=Wrows, B=Xrows) -> D[ch][edge]: lane holds 4 consecutive channels
// of one edge -> 8B packed stores.
// ---------------------------------------------------------------------------
__global__ __launch_bounds__(256) void k1_sxz(
    const float* __restrict__ X, const u16* __restrict__ Wi_b,
    const u16* __restrict__ Wj_b, const float* __restrict__ mb1,
    u16* __restrict__ Xb, u16* __restrict__ Sb, u16* __restrict__ Zb)
{
  const int tid = threadIdx.x, wid = tid >> 6, lane = tid & 63;
  const int r = lane & 15, q = lane >> 4;
  const long e0 = ((long)blockIdx.x * 4 + wid) * 16;
  if (e0 >= NE) return;

  // Load X row r as float4 pairs, convert once, keep as B-frags, write Xb.
  bf16x8 xf[4];
  const float* xp = X + (e0 + r) * ND + q * 8;
  u16* xbp = Xb + (e0 + r) * 256 + q * 8;   // Xb stride 256 (aliased in out)
#pragma unroll
  for (int kk = 0; kk < 4; ++kk) {
    const f32x4 lo = *(const f32x4*)(xp + kk * 32);
    const f32x4 hi = *(const f32x4*)(xp + kk * 32 + 4);
    bf16x8 t;
#pragma unroll
    for (int i = 0; i < 4; ++i) { t[i] = (bf16_t)lo[i]; t[i + 4] = (bf16_t)hi[i]; }
    xf[kk] = t;
    *(bf16x8*)(xbp + kk * 32) = t;
  }

#pragma unroll
  for (int nt = 0; nt < 16; ++nt) {
    const u16* wr = (nt < 8 ? Wi_b + (nt * 16 + r) * ND
                            : Wj_b + ((nt - 8) * 16 + r) * ND) + q * 8;
    f32x4 acc = {0.f, 0.f, 0.f, 0.f};
#pragma unroll
    for (int kk = 0; kk < 4; ++kk) {
      const bf16x8 w = *(const bf16x8*)(wr + kk * 32);
      acc = __builtin_amdgcn_mfma_f32_16x16x32_bf16(w, xf[kk], acc, 0, 0, 0);
    }
    // lane holds D[ch = (nt&7)*16 + q*4 + i][edge = e0+r]
    const int cbase = (nt & 7) * 16 + q * 4;
    bf16x4 pk;
    if (nt < 8) {
      const f32x4 mb = *(const f32x4*)(mb1 + cbase);
#pragma unroll
      for (int i = 0; i < 4; ++i) pk[i] = (bf16_t)(acc[i] + mb[i]);
      *(bf16x4*)(Sb + (e0 + r) * ND + cbase) = pk;
    } else {
#pragma unroll
      for (int i = 0; i < 4; ++i) pk[i] = (bf16_t)acc[i];
      *(bf16x4*)(Zb + (e0 + r) * ND + cbase) = pk;
    }
  }
}

// ---------------------------------------------------------------------------
// k2: hbar[e] = (1/16) * sum_k relu(S[e] + Z[adj[e][k]])
// Wave per edge; 64 lanes x 1 dword = full 256B row per gather instruction.
// ---------------------------------------------------------------------------
__global__ __launch_bounds__(256) void k2_gather(
    const u16* __restrict__ Zb, const u16* __restrict__ Sb,
    const int* __restrict__ adj, u16* __restrict__ Hb)
{
  const int tid = threadIdx.x, wid = tid >> 6, lane = tid & 63;
  const long e = (long)blockIdx.x * 4 + wid;
  if (e >= NE) return;
  const int d0 = lane * 2;

  const unsigned sbits = *(const unsigned*)(Sb + e * ND + d0);
  const float s0 = bf2f(sbits & 0xffffu);
  const float s1 = bf2f(sbits >> 16);

  float acc0 = 0.f, acc1 = 0.f;
  const int* ar = adj + e * NK;
#pragma unroll
  for (int k = 0; k < NK; ++k) {
    const int n = ar[k];
    const unsigned z = *(const unsigned*)(Zb + (long)n * ND + d0);
    acc0 += fmaxf(s0 + bf2f(z & 0xffffu), 0.f);
    acc1 += fmaxf(s1 + bf2f(z >> 16), 0.f);
  }
  const unsigned outw =
      (unsigned)f2bf(acc0 * 0.0625f) | ((unsigned)f2bf(acc1 * 0.0625f) << 16);
  *(unsigned*)(Hb + e * ND + d0) = outw;
}

// ---------------------------------------------------------------------------
// k3: u = relu(Xb@Ui^T + Hb@Wp^T + bp)  [concat K=256 GEMM]
//     out = u @ uW2^T + ub2
// u routed through per-wave XOR-swizzled LDS (D-layout -> B-frag layout).
// Xb aliases out (first 256B of each 512B out row); wave reads its own rows
// before overwriting them.
// ---------------------------------------------------------------------------
__global__ __launch_bounds__(256) void k3_out(
    const u16* __restrict__ Xb, const u16* __restrict__ Hb,
    const u16* __restrict__ Ui_b, const u16* __restrict__ Wp_b,
    const u16* __restrict__ W2_b, const float* __restrict__ bp,
    const float* __restrict__ ub2, float* __restrict__ out)
{
  __shared__ u16 ut[4][16 * ND];
  const int tid = threadIdx.x, wid = tid >> 6, lane = tid & 63;
  const int r = lane & 15, q = lane >> 4;
  const long e0 = ((long)blockIdx.x * 4 + wid) * 16;
  if (e0 >= NE) return;
  u16* lds = ut[wid];

  bf16x8 xf[4], hf[4];
#pragma unroll
  for (int kk = 0; kk < 4; ++kk) {
    xf[kk] = *(const bf16x8*)(Xb + (e0 + r) * 256 + kk * 32 + q * 8);
    hf[kk] = *(const bf16x8*)(Hb + (e0 + r) * ND + kk * 32 + q * 8);
  }

#pragma unroll
  for (int nt = 0; nt < 8; ++nt) {
    f32x4 acc = {0.f, 0.f, 0.f, 0.f};
#pragma unroll
    for (int kk = 0; kk < 4; ++kk) {
      const bf16x8 w = *(const bf16x8*)(Ui_b + (nt * 16 + r) * ND + kk * 32 + q * 8);
      acc = __builtin_amdgcn_mfma_f32_16x16x32_bf16(w, xf[kk], acc, 0, 0, 0);
    }
#pragma unroll
    for (int kk = 0; kk < 4; ++kk) {
      const bf16x8 w = *(const bf16x8*)(Wp_b + (nt * 16 + r) * ND + kk * 32 + q * 8);
      acc = __builtin_amdgcn_mfma_f32_16x16x32_bf16(w, hf[kk], acc, 0, 0, 0);
    }
    const f32x4 bv = *(const f32x4*)(bp + nt * 16 + q * 4);
    bf16x4 u;
#pragma unroll
    for (int i = 0; i < 4; ++i) u[i] = (bf16_t)fmaxf(acc[i] + bv[i], 0.f);
    // lane: edge r, channels nt*16+q*4.. -> swizzled LDS write (8B)
    const int byteoff = r * 256 + ((nt * 32 + q * 8) ^ ((r & 7) << 4));
    *(bf16x4*)((char*)lds + byteoff) = u;
  }

  // B-frags for u from LDS (same XOR swizzle, 16B reads)
  bf16x8 uf[4];
#pragma unroll
  for (int kk = 0; kk < 4; ++kk) {
    const int byteoff = r * 256 + ((kk * 64 + q * 16) ^ ((r & 7) << 4));
    uf[kk] = *(const bf16x8*)((const char*)lds + byteoff);
  }

#pragma unroll
  for (int nt = 0; nt < 8; ++nt) {
    f32x4 acc = {0.f, 0.f, 0.f, 0.f};
#pragma unroll
    for (int kk = 0; kk < 4; ++kk) {
      const bf16x8 w = *(const bf16x8*)(W2_b + (nt * 16 + r) * ND + kk * 32 + q * 8);
      acc = __builtin_amdgcn_mfma_f32_16x16x32_bf16(w, uf[kk], acc, 0, 0, 0);
    }
    const f32x4 bv = *(const f32x4*)(ub2 + nt * 16 + q * 4);
    f32x4 o;
#pragma unroll
    for (int i = 0; i < 4; ++i) o[i] = acc[i] + bv[i];
    *(f32x4*)(out + (e0 + r) * ND + nt * 16 + q * 4) = o;
  }
}

extern "C" void kernel_launch(void* const* d_in, const int* in_sizes, int n_in,
                              void* d_out, int out_size, void* d_ws, size_t ws_size,
                              hipStream_t stream)
{
  (void)in_sizes; (void)n_in; (void)out_size; (void)ws_size;
  const float* X   = (const float*)d_in[0];
  const int*   adj = (const int*)d_in[1];
  const float* mW1 = (const float*)d_in[2];
  const float* mb1 = (const float*)d_in[3];
  const float* mW2 = (const float*)d_in[4];
  const float* mb2 = (const float*)d_in[5];
  const float* uW1 = (const float*)d_in[6];
  const float* ub1 = (const float*)d_in[7];
  const float* uW2 = (const float*)d_in[8];
  const float* ub2 = (const float*)d_in[9];
  float* out = (float*)d_out;

  u16* ws16 = (u16*)d_ws;
  u16* Sb   = ws16;                              // E*D bf16
  u16* Zb   = Sb + (size_t)NE * ND;              // E*D bf16
  u16* Hb   = Zb + (size_t)NE * ND;              // E*D bf16
  u16* Wi_b = Hb + (size_t)NE * ND;              // 128*128 bf16 each:
  u16* Wj_b = Wi_b + 128 * 128;
  u16* Ui_b = Wj_b + 128 * 128;
  u16* Wp_b = Ui_b + 128 * 128;
  u16* W2_b = Wp_b + 128 * 128;
  float* bp = (float*)(W2_b + 128 * 128);        // 128 f32
  u16* Xb   = (u16*)d_out;                       // bf16 X, stride 256, in out rows

  k_prep<<<128, 128, 0, stream>>>(mW1, uW1, uW2, mW2, ub1, mb2,
                                  Wi_b, Wj_b, Ui_b, Wp_b, W2_b, bp);

  const int nblk_gemm = (NE / 16 + 3) / 4;  // 1563
  k1_sxz<<<nblk_gemm, 256, 0, stream>>>(X, Wi_b, Wj_b, mb1, Xb, Sb, Zb);

  const int nblk_gather = (NE + 3) / 4;     // 25000
  k2_gather<<<nblk_gather, 256, 0, stream>>>(Zb, Sb, adj, Hb);

  k3_out<<<nblk_gemm, 256, 0, stream>>>(Xb, Hb, Ui_b, Wp_b, W2_b, bp, ub2, out);
}

// Round 3
// 143.664 us; speedup vs baseline: 2.2181x; 1.5662x over previous
//
#include <hip/hip_runtime.h>
#include <hip/hip_bf16.h>

#define NE 100000
#define NK 16
#define ND 128
#define NTILES 6250   // NE / 16

typedef __bf16 bf16_t;
typedef bf16_t bf16x8 __attribute__((ext_vector_type(8)));
typedef bf16_t bf16x4 __attribute__((ext_vector_type(4)));
typedef float f32x4 __attribute__((ext_vector_type(4)));
typedef unsigned short u16;

__device__ __forceinline__ u16 f2bf(float f) {
  bf16_t h = (bf16_t)f;
  return __builtin_bit_cast(u16, h);
}
__device__ __forceinline__ float bf2f(unsigned int bits) {
  return __builtin_bit_cast(float, bits << 16);
}

// ---------------------------------------------------------------------------
// k_prep: bf16-convert weights; fold Wp = Um@mW2, bp = ub1 + Um@mb2.
// ---------------------------------------------------------------------------
__global__ void k_prep(const float* __restrict__ mW1, const float* __restrict__ uW1,
                       const float* __restrict__ uW2, const float* __restrict__ mW2,
                       const float* __restrict__ ub1, const float* __restrict__ mb2,
                       u16* __restrict__ Wi_b, u16* __restrict__ Wj_b,
                       u16* __restrict__ Ui_b, u16* __restrict__ Wp_b,
                       u16* __restrict__ W2_b, float* __restrict__ bp)
{
  const int o = blockIdx.x, t = threadIdx.x;
  Wi_b[o * ND + t] = f2bf(mW1[o * 256 + t]);
  Wj_b[o * ND + t] = f2bf(mW1[o * 256 + 128 + t]);
  Ui_b[o * ND + t] = f2bf(uW1[o * 256 + t]);
  W2_b[o * ND + t] = f2bf(uW2[o * ND + t]);
  float acc = 0.f;
  for (int p = 0; p < 128; ++p)
    acc += uW1[o * 256 + 128 + p] * mW2[p * 128 + t];
  Wp_b[o * ND + t] = f2bf(acc);
  if (t == 0) {
    float b = ub1[o];
    for (int p = 0; p < 128; ++p) b += uW1[o * 256 + 128 + p] * mb2[p];
    bp[o] = b;
  }
}

// ---------------------------------------------------------------------------
// k1: S = X@Wi^T + mb1 (bf16), Z = X@Wj^T (bf16), T1 = X@Ui^T + bp (bf16,
// stored in out rows at u16-stride 256). Wave w keeps Wi/Wj/Ui nt-tiles
// {2w,2w+1} register-resident; block grid-strides over edge tiles with
// next-tile X prefetch. 3 independent MFMA chains per j hide MFMA latency.
// ---------------------------------------------------------------------------
__global__ __launch_bounds__(256) void k1_szt(
    const float* __restrict__ X, const u16* __restrict__ Wi_b,
    const u16* __restrict__ Wj_b, const u16* __restrict__ Ui_b,
    const float* __restrict__ mb1, const float* __restrict__ bp,
    u16* __restrict__ Sb, u16* __restrict__ Zb, u16* __restrict__ T1)
{
  const int tid = threadIdx.x, wid = tid >> 6, lane = tid & 63;
  const int r = lane & 15, q = lane >> 4;

  bf16x8 wiF[2][4], wjF[2][4], uiF[2][4];
  f32x4 mbF[2], bpF[2];
#pragma unroll
  for (int j = 0; j < 2; ++j) {
    const int row = (2 * wid + j) * 16 + r;
#pragma unroll
    for (int kk = 0; kk < 4; ++kk) {
      wiF[j][kk] = *(const bf16x8*)(Wi_b + row * ND + kk * 32 + q * 8);
      wjF[j][kk] = *(const bf16x8*)(Wj_b + row * ND + kk * 32 + q * 8);
      uiF[j][kk] = *(const bf16x8*)(Ui_b + row * ND + kk * 32 + q * 8);
    }
    mbF[j] = *(const f32x4*)(mb1 + (2 * wid + j) * 16 + q * 4);
    bpF[j] = *(const f32x4*)(bp  + (2 * wid + j) * 16 + q * 4);
  }

  const long stride = gridDim.x;
  long t = blockIdx.x;
  if (t >= NTILES) return;

  f32x4 xraw[8];
  auto loadx = [&](long tt) {
    const float* xp = X + (tt * 16 + r) * ND + q * 8;
#pragma unroll
    for (int kk = 0; kk < 4; ++kk) {
      xraw[2 * kk]     = *(const f32x4*)(xp + kk * 32);
      xraw[2 * kk + 1] = *(const f32x4*)(xp + kk * 32 + 4);
    }
  };
  loadx(t);

  for (; t < NTILES; t += stride) {
    bf16x8 xf[4];
#pragma unroll
    for (int kk = 0; kk < 4; ++kk) {
      bf16x8 v;
#pragma unroll
      for (int i = 0; i < 4; ++i) {
        v[i]     = (bf16_t)xraw[2 * kk][i];
        v[i + 4] = (bf16_t)xraw[2 * kk + 1][i];
      }
      xf[kk] = v;
    }
    const long tn = t + stride;
    if (tn < NTILES) loadx(tn);   // prefetch next tile while MFMAs run

    const long rowS = (t * 16 + r) * ND;
    const long rowT = (t * 16 + r) * 256;
#pragma unroll
    for (int j = 0; j < 2; ++j) {
      f32x4 aS = {0.f, 0.f, 0.f, 0.f};
      f32x4 aZ = {0.f, 0.f, 0.f, 0.f};
      f32x4 aT = {0.f, 0.f, 0.f, 0.f};
#pragma unroll
      for (int kk = 0; kk < 4; ++kk) {
        aS = __builtin_amdgcn_mfma_f32_16x16x32_bf16(wiF[j][kk], xf[kk], aS, 0, 0, 0);
        aZ = __builtin_amdgcn_mfma_f32_16x16x32_bf16(wjF[j][kk], xf[kk], aZ, 0, 0, 0);
        aT = __builtin_amdgcn_mfma_f32_16x16x32_bf16(uiF[j][kk], xf[kk], aT, 0, 0, 0);
      }
      const int cb = (2 * wid + j) * 16 + q * 4;
      bf16x4 pS, pZ, pT;
#pragma unroll
      for (int i = 0; i < 4; ++i) {
        pS[i] = (bf16_t)(aS[i] + mbF[j][i]);
        pZ[i] = (bf16_t)aZ[i];
        pT[i] = (bf16_t)(aT[i] + bpF[j][i]);
      }
      *(bf16x4*)(Sb + rowS + cb) = pS;
      *(bf16x4*)(Zb + rowS + cb) = pZ;
      *(bf16x4*)(T1 + rowT + cb) = pT;
    }
  }
}

// ---------------------------------------------------------------------------
// k2: hbar[e] = (1/16) * sum_k relu(S[e] + Z[adj[e][k]])
// Wave per edge; 64 lanes x 1 dword = full 256B row per gather instruction.
// ---------------------------------------------------------------------------
__global__ __launch_bounds__(256) void k2_gather(
    const u16* __restrict__ Zb, const u16* __restrict__ Sb,
    const int* __restrict__ adj, u16* __restrict__ Hb)
{
  const int tid = threadIdx.x, wid = tid >> 6, lane = tid & 63;
  const long e = (long)blockIdx.x * 4 + wid;
  if (e >= NE) return;
  const int d0 = lane * 2;

  const unsigned sbits = *(const unsigned*)(Sb + e * ND + d0);
  const float s0 = bf2f(sbits & 0xffffu);
  const float s1 = bf2f(sbits >> 16);

  float acc0 = 0.f, acc1 = 0.f;
  const int* ar = adj + e * NK;
#pragma unroll
  for (int k = 0; k < NK; ++k) {
    const int n = ar[k];
    const unsigned z = *(const unsigned*)(Zb + (long)n * ND + d0);
    acc0 += fmaxf(s0 + bf2f(z & 0xffffu), 0.f);
    acc1 += fmaxf(s1 + bf2f(z >> 16), 0.f);
  }
  const unsigned outw =
      (unsigned)f2bf(acc0 * 0.0625f) | ((unsigned)f2bf(acc1 * 0.0625f) << 16);
  *(unsigned*)(Hb + e * ND + d0) = outw;
}

// ---------------------------------------------------------------------------
// k3: u = relu(T1 + Hb@Wp^T); out = u@uW2^T + ub2.
// Wave w keeps Wp/W2 nt-tiles {2w,2w+1} register-resident. Cross-wave u
// exchange via double-buffered swizzled LDS tile (one barrier per tile).
// T1 aliases out rows (read-before-overwrite enforced by the barrier).
// ---------------------------------------------------------------------------
__global__ __launch_bounds__(256) void k3_out(
    const u16* __restrict__ Hb, const u16* __restrict__ T1,
    const u16* __restrict__ Wp_b, const u16* __restrict__ W2_b,
    const float* __restrict__ ub2, float* __restrict__ out)
{
  __shared__ u16 ubuf[2][16 * ND];
  const int tid = threadIdx.x, wid = tid >> 6, lane = tid & 63;
  const int r = lane & 15, q = lane >> 4;
  const int swz = (r & 7) << 4;

  bf16x8 wpF[2][4], w2F[2][4];
  f32x4 ubF[2];
#pragma unroll
  for (int j = 0; j < 2; ++j) {
    const int row = (2 * wid + j) * 16 + r;
#pragma unroll
    for (int kk = 0; kk < 4; ++kk) {
      wpF[j][kk] = *(const bf16x8*)(Wp_b + row * ND + kk * 32 + q * 8);
      w2F[j][kk] = *(const bf16x8*)(W2_b + row * ND + kk * 32 + q * 8);
    }
    ubF[j] = *(const f32x4*)(ub2 + (2 * wid + j) * 16 + q * 4);
  }

  const long stride = gridDim.x;
  long t = blockIdx.x;
  if (t >= NTILES) return;

  bf16x8 hraw[4];
  bf16x4 traw[2];
  auto loadin = [&](long tt) {
#pragma unroll
    for (int kk = 0; kk < 4; ++kk)
      hraw[kk] = *(const bf16x8*)(Hb + (tt * 16 + r) * ND + kk * 32 + q * 8);
#pragma unroll
    for (int j = 0; j < 2; ++j)
      traw[j] = *(const bf16x4*)(T1 + (tt * 16 + r) * 256 + (2 * wid + j) * 16 + q * 4);
  };
  loadin(t);
  int buf = 0;

  for (; t < NTILES; t += stride) {
    bf16x8 hf[4];
#pragma unroll
    for (int kk = 0; kk < 4; ++kk) hf[kk] = hraw[kk];
    f32x4 acc[2];
#pragma unroll
    for (int j = 0; j < 2; ++j)
#pragma unroll
      for (int i = 0; i < 4; ++i) acc[j][i] = (float)traw[j][i];

    const long tn = t + stride;
    if (tn < NTILES) loadin(tn);   // prefetch next tile (disjoint rows)

#pragma unroll
    for (int j = 0; j < 2; ++j)
#pragma unroll
      for (int kk = 0; kk < 4; ++kk)
        acc[j] = __builtin_amdgcn_mfma_f32_16x16x32_bf16(wpF[j][kk], hf[kk], acc[j], 0, 0, 0);

#pragma unroll
    for (int j = 0; j < 2; ++j) {
      bf16x4 u;
#pragma unroll
      for (int i = 0; i < 4; ++i) u[i] = (bf16_t)fmaxf(acc[j][i], 0.f);
      const int byteoff = r * 256 + ((((2 * wid + j) * 32) + q * 8) ^ swz);
      *(bf16x4*)((char*)ubuf[buf] + byteoff) = u;
    }
    __syncthreads();

    bf16x8 uf[4];
#pragma unroll
    for (int kk = 0; kk < 4; ++kk) {
      const int byteoff = r * 256 + ((kk * 64 + q * 16) ^ swz);
      uf[kk] = *(const bf16x8*)((const char*)ubuf[buf] + byteoff);
    }

    const long e0 = t * 16;
#pragma unroll
    for (int j = 0; j < 2; ++j) {
      f32x4 o = {0.f, 0.f, 0.f, 0.f};
#pragma unroll
      for (int kk = 0; kk < 4; ++kk)
        o = __builtin_amdgcn_mfma_f32_16x16x32_bf16(w2F[j][kk], uf[kk], o, 0, 0, 0);
#pragma unroll
      for (int i = 0; i < 4; ++i) o[i] += ubF[j][i];
      *(f32x4*)(out + (e0 + r) * ND + (2 * wid + j) * 16 + q * 4) = o;
    }
    buf ^= 1;
  }
}

extern "C" void kernel_launch(void* const* d_in, const int* in_sizes, int n_in,
                              void* d_out, int out_size, void* d_ws, size_t ws_size,
                              hipStream_t stream)
{
  (void)in_sizes; (void)n_in; (void)out_size; (void)ws_size;
  const float* X   = (const float*)d_in[0];
  const int*   adj = (const int*)d_in[1];
  const float* mW1 = (const float*)d_in[2];
  const float* mb1 = (const float*)d_in[3];
  const float* mW2 = (const float*)d_in[4];
  const float* mb2 = (const float*)d_in[5];
  const float* uW1 = (const float*)d_in[6];
  const float* ub1 = (const float*)d_in[7];
  const float* uW2 = (const float*)d_in[8];
  const float* ub2 = (const float*)d_in[9];
  float* out = (float*)d_out;

  u16* ws16 = (u16*)d_ws;
  u16* Sb   = ws16;                              // E*D bf16
  u16* Zb   = Sb + (size_t)NE * ND;              // E*D bf16
  u16* Hb   = Zb + (size_t)NE * ND;              // E*D bf16
  u16* Wi_b = Hb + (size_t)NE * ND;              // 128*128 bf16 each:
  u16* Wj_b = Wi_b + 128 * 128;
  u16* Ui_b = Wj_b + 128 * 128;
  u16* Wp_b = Ui_b + 128 * 128;
  u16* W2_b = Wp_b + 128 * 128;
  float* bp = (float*)(W2_b + 128 * 128);        // 128 f32
  u16* T1   = (u16*)d_out;                       // bf16 T1, stride 256, in out rows

  k_prep<<<128, 128, 0, stream>>>(mW1, uW1, uW2, mW2, ub1, mb2,
                                  Wi_b, Wj_b, Ui_b, Wp_b, W2_b, bp);

  k1_szt<<<768, 256, 0, stream>>>(X, Wi_b, Wj_b, Ui_b, mb1, bp, Sb, Zb, T1);

  const int nblk_gather = (NE + 3) / 4;     // 25000
  k2_gather<<<nblk_gather, 256, 0, stream>>>(Zb, Sb, adj, Hb);

  k3_out<<<768, 256, 0, stream>>>(Hb, T1, Wp_b, W2_b, ub2, out);
}